// Round 1
// baseline (2411.952 us; speedup 1.0000x reference)
//
#include <hip/hip_runtime.h>
#include <cstdint>

#define NNODES 80000
#define NEDGES 1280000
#define INDIM 32
#define EDIM 16
#define HID 64
#define HID2 128
#define DEPTH 4
#define BN_EPS 1e-5f
#define LN_EPS 1e-5f
#define NB 313         // ceil(80000/256)
#define NPW 16         // nodes per wave in MLP kernels

__device__ __forceinline__ float wave_sum64(float v) {
#pragma unroll
    for (int o = 32; o > 0; o >>= 1) v += __shfl_xor(v, o, 64);
    return v;
}

// h = relu(x @ Wx + bx); one wave per node, lane = out channel
__global__ __launch_bounds__(256) void k_node_embed(
    const float* __restrict__ x, const float* __restrict__ Wx,
    const float* __restrict__ bx, float* __restrict__ h) {
    int gw = (blockIdx.x * 256 + threadIdx.x) >> 6;
    int lane = threadIdx.x & 63;
    if (gw >= NNODES) return;
    float xv = (lane < INDIM) ? x[(size_t)gw * INDIM + lane] : 0.f;
    float acc = bx[lane];
#pragma unroll
    for (int k = 0; k < INDIM; k++)
        acc = fmaf(__shfl(xv, k, 64), Wx[k * HID + lane], acc);
    h[(size_t)gw * HID + lane] = fmaxf(acc, 0.f);
}

__global__ __launch_bounds__(256) void k_hist(const int* __restrict__ col, int* __restrict__ deg) {
    int e = blockIdx.x * 256 + threadIdx.x;
    if (e < NEDGES) atomicAdd(&deg[col[e]], 1);
}

__global__ __launch_bounds__(256) void k_scan1(const int* __restrict__ deg, int* __restrict__ bsum) {
    __shared__ int s[256];
    int i = blockIdx.x * 256 + threadIdx.x;
    int v = (i < NNODES) ? deg[i] : 0;
    s[threadIdx.x] = v;
    __syncthreads();
    for (int o = 128; o > 0; o >>= 1) {
        if (threadIdx.x < o) s[threadIdx.x] += s[threadIdx.x + o];
        __syncthreads();
    }
    if (threadIdx.x == 0) bsum[blockIdx.x] = s[0];
}

__global__ __launch_bounds__(512) void k_scan2(const int* __restrict__ bsum, int* __restrict__ boff) {
    __shared__ int s[512];
    int t = threadIdx.x;
    s[t] = (t < NB) ? bsum[t] : 0;
    __syncthreads();
    for (int o = 1; o < 512; o <<= 1) {
        int v = (t >= o) ? s[t - o] : 0;
        __syncthreads();
        s[t] += v;
        __syncthreads();
    }
    if (t < NB) boff[t] = (t == 0) ? 0 : s[t - 1];
}

__global__ __launch_bounds__(256) void k_scan3(const int* __restrict__ deg,
                                               const int* __restrict__ boff,
                                               int* __restrict__ row_off) {
    __shared__ int s[256];
    int i = blockIdx.x * 256 + threadIdx.x;
    int t = threadIdx.x;
    int v = (i < NNODES) ? deg[i] : 0;
    s[t] = v;
    __syncthreads();
    for (int o = 1; o < 256; o <<= 1) {
        int u = (t >= o) ? s[t - o] : 0;
        __syncthreads();
        s[t] += u;
        __syncthreads();
    }
    int incl = s[t];
    if (i < NNODES) row_off[i] = boff[blockIdx.x] + incl - v;
    if (i == NNODES - 1) row_off[NNODES] = boff[blockIdx.x] + incl;
}

__global__ __launch_bounds__(256) void k_copy(const int* __restrict__ src, int* __restrict__ dst) {
    int i = blockIdx.x * 256 + threadIdx.x;
    if (i < NNODES) dst[i] = src[i];
}

__global__ __launch_bounds__(256) void k_scatter(const int* __restrict__ row,
                                                 const int* __restrict__ col,
                                                 int* __restrict__ cursor,
                                                 int* __restrict__ srow,
                                                 int* __restrict__ seid) {
    int e = blockIdx.x * 256 + threadIdx.x;
    if (e < NEDGES) {
        int c = col[e];
        int pos = atomicAdd(&cursor[c], 1);
        srow[pos] = row[e];
        seid[pos] = e;
    }
}

// permute edge_attr into CSR order (coalesced per-layer streaming later)
__global__ __launch_bounds__(256) void k_eas(const float* __restrict__ eat,
                                             const int* __restrict__ seid,
                                             float* __restrict__ eas) {
    size_t idx = (size_t)blockIdx.x * 256 + threadIdx.x;
    if (idx >= (size_t)NEDGES * EDIM) return;
    int p = (int)(idx >> 4);
    int k = (int)(idx & 15);
    eas[idx] = eat[(size_t)seid[p] * EDIM + k];
}

// per layer: zc[i] = (1+eps)*h[i] + sum_{e: col=i} relu(h[row_e] + relu(ea_e@We+be))
__global__ __launch_bounds__(256) void k_msg(
    const float* __restrict__ h, const int* __restrict__ row_off,
    const int* __restrict__ srow, const float* __restrict__ eas,
    const float* __restrict__ We, const float* __restrict__ be,
    const float* __restrict__ epsp, float* __restrict__ zc) {
    int gw = (blockIdx.x * 256 + threadIdx.x) >> 6;
    int lane = threadIdx.x & 63;
    if (gw >= NNODES) return;
    float wreg[EDIM];
#pragma unroll
    for (int k = 0; k < EDIM; k++) wreg[k] = We[k * HID + lane];
    float breg = be[lane];
    int beg = row_off[gw], end = row_off[gw + 1];
    float acc = 0.f;
    for (int e = beg; e < end; ++e) {
        int j = srow[e];
        float hv = h[(size_t)j * HID + lane];
        float ev = (lane < EDIM) ? eas[(size_t)e * EDIM + lane] : 0.f;
        float v = breg;
#pragma unroll
        for (int k = 0; k < EDIM; k++) v = fmaf(__shfl(ev, k, 64), wreg[k], v);
        v = fmaxf(v, 0.f);
        acc += fmaxf(hv + v, 0.f);
    }
    float epsl = *epsp;
    float hv0 = h[(size_t)gw * HID + lane];
    zc[(size_t)gw * HID + lane] = (1.f + epsl) * hv0 + acc;
}

// z1 = zc @ W1 + b1 ; accumulate BN sums
__global__ __launch_bounds__(256) void k_gemm1(
    const float* __restrict__ zc, const float* __restrict__ W1l,
    const float* __restrict__ b1l, float* __restrict__ z1,
    float* __restrict__ bn_acc) {
    __shared__ float w[HID * HID2];
    for (int i = threadIdx.x; i < HID * HID2; i += 256) w[i] = W1l[i];
    __syncthreads();
    int lane = threadIdx.x & 63;
    int gw = (blockIdx.x * 256 + threadIdx.x) >> 6;
    int base = gw * NPW;
    float bb0 = b1l[lane], bb1 = b1l[64 + lane];
    float s0 = 0.f, q0 = 0.f, s1 = 0.f, q1 = 0.f;
    for (int t = 0; t < NPW; ++t) {
        int i = base + t;
        if (i >= NNODES) break;
        float z = zc[(size_t)i * HID + lane];
        float a0 = bb0, a1 = bb1;
#pragma unroll
        for (int k = 0; k < HID; k++) {
            float s = __shfl(z, k, 64);
            a0 = fmaf(s, w[k * HID2 + lane], a0);
            a1 = fmaf(s, w[k * HID2 + 64 + lane], a1);
        }
        z1[(size_t)i * HID2 + lane] = a0;
        z1[(size_t)i * HID2 + 64 + lane] = a1;
        s0 += a0; q0 = fmaf(a0, a0, q0);
        s1 += a1; q1 = fmaf(a1, a1, q1);
    }
    atomicAdd(&bn_acc[lane], s0);
    atomicAdd(&bn_acc[64 + lane], s1);
    atomicAdd(&bn_acc[128 + lane], q0);
    atomicAdd(&bn_acc[192 + lane], q1);
}

__global__ void k_bnfin(const float* __restrict__ bn_acc,
                        const float* __restrict__ g1l,
                        const float* __restrict__ bt1l,
                        float* __restrict__ bn_sc) {
    int c = threadIdx.x;
    if (c >= HID2) return;
    float inv_n = 1.f / (float)NNODES;
    float mu = bn_acc[c] * inv_n;
    float ex2 = bn_acc[128 + c] * inv_n;
    float var = ex2 - mu * mu;
    float rs = rsqrtf(var + BN_EPS);
    float sc = g1l[c] * rs;
    bn_sc[c] = sc;
    bn_sc[128 + c] = bt1l[c] - mu * sc;
}

// y = relu(BN(z1)); out = LN(y @ W2 + b2); optional relu
__global__ __launch_bounds__(256) void k_mlp2(
    const float* __restrict__ z1, const float* __restrict__ bn_sc,
    const float* __restrict__ W2l, const float* __restrict__ b2l,
    const float* __restrict__ lngl, const float* __restrict__ lnbl,
    int do_relu, float* __restrict__ out) {
    __shared__ float w[HID2 * HID];
    for (int i = threadIdx.x; i < HID2 * HID; i += 256) w[i] = W2l[i];
    __syncthreads();
    int lane = threadIdx.x & 63;
    int gw = (blockIdx.x * 256 + threadIdx.x) >> 6;
    int base = gw * NPW;
    float sc0 = bn_sc[lane], sc1 = bn_sc[64 + lane];
    float sh0 = bn_sc[128 + lane], sh1 = bn_sc[192 + lane];
    float bb = b2l[lane], lg = lngl[lane], lb = lnbl[lane];
    for (int t = 0; t < NPW; ++t) {
        int i = base + t;
        if (i >= NNODES) break;
        float y0 = fmaxf(fmaf(z1[(size_t)i * HID2 + lane], sc0, sh0), 0.f);
        float y1 = fmaxf(fmaf(z1[(size_t)i * HID2 + 64 + lane], sc1, sh1), 0.f);
        float a = bb;
#pragma unroll
        for (int k = 0; k < 64; k++)
            a = fmaf(__shfl(y0, k, 64), w[k * HID + lane], a);
#pragma unroll
        for (int k = 0; k < 64; k++)
            a = fmaf(__shfl(y1, k, 64), w[(64 + k) * HID + lane], a);
        float m = wave_sum64(a) * (1.f / 64.f);
        float t0 = a - m;
        float v = wave_sum64(t0 * t0) * (1.f / 64.f);
        float o = t0 * rsqrtf(v + LN_EPS) * lg + lb;
        if (do_relu) o = fmaxf(o, 0.f);
        out[(size_t)i * HID + lane] = o;
    }
}

extern "C" void kernel_launch(void* const* d_in, const int* in_sizes, int n_in,
                              void* d_out, int out_size, void* d_ws, size_t ws_size,
                              hipStream_t stream) {
    const float* x   = (const float*)d_in[0];
    const int*   ei  = (const int*)d_in[1];
    const float* eat = (const float*)d_in[2];
    const float* Wx  = (const float*)d_in[3];
    const float* bx  = (const float*)d_in[4];
    const float* We  = (const float*)d_in[5];
    const float* be  = (const float*)d_in[6];
    const float* W1  = (const float*)d_in[7];
    const float* b1  = (const float*)d_in[8];
    const float* g1  = (const float*)d_in[9];
    const float* bt1 = (const float*)d_in[10];
    const float* W2  = (const float*)d_in[11];
    const float* b2  = (const float*)d_in[12];
    const float* eps = (const float*)d_in[13];
    const float* lng = (const float*)d_in[14];
    const float* lnb = (const float*)d_in[15];
    const int* row = ei;
    const int* col = ei + NEDGES;

    char* p = (char*)d_ws;
    auto alloc = [&](size_t bytes) -> char* {
        char* r = p;
        p += (bytes + 255) & ~(size_t)255;
        return r;
    };
    float* h       = (float*)alloc((size_t)NNODES * HID * 4);
    float* zc      = (float*)alloc((size_t)NNODES * HID * 4);
    float* z1      = (float*)alloc((size_t)NNODES * HID2 * 4);
    int*   row_off = (int*)alloc((size_t)(NNODES + 1) * 4);
    int*   cursor  = (int*)alloc((size_t)NNODES * 4);
    int*   bsum    = (int*)alloc((size_t)NB * 4);
    int*   boff    = (int*)alloc((size_t)NB * 4);
    int*   srow    = (int*)alloc((size_t)NEDGES * 4);
    int*   seid    = (int*)alloc((size_t)NEDGES * 4);
    float* eas     = (float*)alloc((size_t)NEDGES * EDIM * 4);
    float* bn_acc  = (float*)alloc(256 * 4);
    float* bn_sc   = (float*)alloc(256 * 4);
    (void)ws_size; (void)in_sizes; (void)n_in; (void)out_size;

    // ---- one-time per call: node embed + CSR build + edge_attr permute ----
    hipMemsetAsync(cursor, 0, (size_t)NNODES * 4, stream);
    k_node_embed<<<(NNODES + 3) / 4, 256, 0, stream>>>(x, Wx, bx, h);
    k_hist<<<(NEDGES + 255) / 256, 256, 0, stream>>>(col, cursor);
    k_scan1<<<NB, 256, 0, stream>>>(cursor, bsum);
    k_scan2<<<1, 512, 0, stream>>>(bsum, boff);
    k_scan3<<<NB, 256, 0, stream>>>(cursor, boff, row_off);
    k_copy<<<NB, 256, 0, stream>>>(row_off, cursor);
    k_scatter<<<(NEDGES + 255) / 256, 256, 0, stream>>>(row, col, cursor, srow, seid);
    k_eas<<<(int)(((size_t)NEDGES * EDIM + 255) / 256), 256, 0, stream>>>(eat, seid, eas);

    // ---- layers ----
    const int msg_blocks = (NNODES + 3) / 4;
    const int mlp_blocks = ((NNODES + NPW - 1) / NPW + 3) / 4;
    for (int l = 0; l < DEPTH; ++l) {
        k_msg<<<msg_blocks, 256, 0, stream>>>(h, row_off, srow, eas, We, be, eps + l, zc);
        hipMemsetAsync(bn_acc, 0, 256 * 4, stream);
        k_gemm1<<<mlp_blocks, 256, 0, stream>>>(zc, W1 + (size_t)l * HID * HID2,
                                                b1 + (size_t)l * HID2, z1, bn_acc);
        k_bnfin<<<1, 128, 0, stream>>>(bn_acc, g1 + (size_t)l * HID2,
                                       bt1 + (size_t)l * HID2, bn_sc);
        float* outp = (l == DEPTH - 1) ? (float*)d_out : h;
        k_mlp2<<<mlp_blocks, 256, 0, stream>>>(z1, bn_sc, W2 + (size_t)l * HID2 * HID,
                                               b2 + (size_t)l * HID,
                                               lng + (size_t)l * HID, lnb + (size_t)l * HID,
                                               (l < DEPTH - 1) ? 1 : 0, outp);
    }
}

// Round 2
// 2051.965 us; speedup vs baseline: 1.1754x; 1.1754x over previous
//
#include <hip/hip_runtime.h>
#include <hip/hip_bf16.h>
#include <cstdint>

#define NNODES 80000
#define NEDGES 1280000
#define INDIM 32
#define EDIM 16
#define HID 64
#define HID2 128
#define DEPTH 4
#define BN_EPS 1e-5f
#define LN_EPS 1e-5f
#define NB 313         // ceil(80000/256)
#define NPW 16         // nodes per wave in MLP kernels

__device__ __forceinline__ float wave_sum64(float v) {
#pragma unroll
    for (int o = 32; o > 0; o >>= 1) v += __shfl_xor(v, o, 64);
    return v;
}

__device__ __forceinline__ float bf2f(unsigned short u) {
    union { float f; uint32_t i; } c;
    c.i = ((uint32_t)u) << 16;
    return c.f;
}

// h = relu(x @ Wx + bx); one wave per node, lane = out channel
__global__ __launch_bounds__(256) void k_node_embed(
    const float* __restrict__ x, const float* __restrict__ Wx,
    const float* __restrict__ bx, float* __restrict__ h) {
    int gw = (blockIdx.x * 256 + threadIdx.x) >> 6;
    int lane = threadIdx.x & 63;
    if (gw >= NNODES) return;
    float xv = (lane < INDIM) ? x[(size_t)gw * INDIM + lane] : 0.f;
    float acc = bx[lane];
#pragma unroll
    for (int k = 0; k < INDIM; k++)
        acc = fmaf(__shfl(xv, k, 64), Wx[k * HID + lane], acc);
    h[(size_t)gw * HID + lane] = fmaxf(acc, 0.f);
}

__global__ __launch_bounds__(256) void k_hist(const int* __restrict__ col, int* __restrict__ deg) {
    int e = blockIdx.x * 256 + threadIdx.x;
    if (e < NEDGES) atomicAdd(&deg[col[e]], 1);
}

__global__ __launch_bounds__(256) void k_scan1(const int* __restrict__ deg, int* __restrict__ bsum) {
    __shared__ int s[256];
    int i = blockIdx.x * 256 + threadIdx.x;
    int v = (i < NNODES) ? deg[i] : 0;
    s[threadIdx.x] = v;
    __syncthreads();
    for (int o = 128; o > 0; o >>= 1) {
        if (threadIdx.x < o) s[threadIdx.x] += s[threadIdx.x + o];
        __syncthreads();
    }
    if (threadIdx.x == 0) bsum[blockIdx.x] = s[0];
}

__global__ __launch_bounds__(512) void k_scan2(const int* __restrict__ bsum, int* __restrict__ boff) {
    __shared__ int s[512];
    int t = threadIdx.x;
    s[t] = (t < NB) ? bsum[t] : 0;
    __syncthreads();
    for (int o = 1; o < 512; o <<= 1) {
        int v = (t >= o) ? s[t - o] : 0;
        __syncthreads();
        s[t] += v;
        __syncthreads();
    }
    if (t < NB) boff[t] = (t == 0) ? 0 : s[t - 1];
}

__global__ __launch_bounds__(256) void k_scan3(const int* __restrict__ deg,
                                               const int* __restrict__ boff,
                                               int* __restrict__ row_off) {
    __shared__ int s[256];
    int i = blockIdx.x * 256 + threadIdx.x;
    int t = threadIdx.x;
    int v = (i < NNODES) ? deg[i] : 0;
    s[t] = v;
    __syncthreads();
    for (int o = 1; o < 256; o <<= 1) {
        int u = (t >= o) ? s[t - o] : 0;
        __syncthreads();
        s[t] += u;
        __syncthreads();
    }
    int incl = s[t];
    if (i < NNODES) row_off[i] = boff[blockIdx.x] + incl - v;
    if (i == NNODES - 1) row_off[NNODES] = boff[blockIdx.x] + incl;
}

__global__ __launch_bounds__(256) void k_copy(const int* __restrict__ src, int* __restrict__ dst) {
    int i = blockIdx.x * 256 + threadIdx.x;
    if (i < NNODES) dst[i] = src[i];
}

__global__ __launch_bounds__(256) void k_scatter(const int* __restrict__ row,
                                                 const int* __restrict__ col,
                                                 int* __restrict__ cursor,
                                                 int* __restrict__ srow,
                                                 int* __restrict__ seid) {
    int e = blockIdx.x * 256 + threadIdx.x;
    if (e < NEDGES) {
        int c = col[e];
        int pos = atomicAdd(&cursor[c], 1);
        srow[pos] = row[e];
        seid[pos] = e;
    }
}

// ea[pos] = relu(edge_attr[seid[pos]] @ We + be), bf16, CSR order. One wave/edge.
__global__ __launch_bounds__(256) void k_edge_embed(
    const float* __restrict__ eat, const int* __restrict__ seid,
    const float* __restrict__ We, const float* __restrict__ be,
    unsigned short* __restrict__ eas) {
    int pos = (blockIdx.x * 256 + threadIdx.x) >> 6;
    int lane = threadIdx.x & 63;
    if (pos >= NEDGES) return;
    int e = seid[pos];
    float ev = (lane < EDIM) ? eat[(size_t)e * EDIM + lane] : 0.f;
    float v = be[lane];
#pragma unroll
    for (int k = 0; k < EDIM; k++)
        v = fmaf(__shfl(ev, k, 64), We[k * HID + lane], v);
    v = fmaxf(v, 0.f);
    __hip_bfloat16 b = __float2bfloat16(v);
    eas[(size_t)pos * HID + lane] = *(unsigned short*)&b;
}

// zc[i] = (1+eps)*h[i] + sum_{e in CSR[i]} relu(h[srow[e]] + ea[e])
__global__ __launch_bounds__(256) void k_msg(
    const float* __restrict__ h, const int* __restrict__ row_off,
    const int* __restrict__ srow, const unsigned short* __restrict__ eas,
    const float* __restrict__ epsp, float* __restrict__ zc) {
    int gw = (blockIdx.x * 256 + threadIdx.x) >> 6;
    int lane = threadIdx.x & 63;
    if (gw >= NNODES) return;
    int beg = row_off[gw], end = row_off[gw + 1];
    float acc = 0.f;
    int e = beg;
    for (; e + 3 < end; e += 4) {
        int j0 = srow[e], j1 = srow[e + 1], j2 = srow[e + 2], j3 = srow[e + 3];
        float h0 = h[(size_t)j0 * HID + lane];
        float h1 = h[(size_t)j1 * HID + lane];
        float h2 = h[(size_t)j2 * HID + lane];
        float h3 = h[(size_t)j3 * HID + lane];
        float e0 = bf2f(eas[(size_t)(e + 0) * HID + lane]);
        float e1 = bf2f(eas[(size_t)(e + 1) * HID + lane]);
        float e2 = bf2f(eas[(size_t)(e + 2) * HID + lane]);
        float e3 = bf2f(eas[(size_t)(e + 3) * HID + lane]);
        acc += (fmaxf(h0 + e0, 0.f) + fmaxf(h1 + e1, 0.f)) +
               (fmaxf(h2 + e2, 0.f) + fmaxf(h3 + e3, 0.f));
    }
    for (; e < end; ++e) {
        int j = srow[e];
        float hv = h[(size_t)j * HID + lane];
        float ev = bf2f(eas[(size_t)e * HID + lane]);
        acc += fmaxf(hv + ev, 0.f);
    }
    float epsl = *epsp;
    float hv0 = h[(size_t)gw * HID + lane];
    zc[(size_t)gw * HID + lane] = (1.f + epsl) * hv0 + acc;
}

// z1 = zc @ W1 + b1 ; accumulate BN sums. 4 independent FMA chains per output.
__global__ __launch_bounds__(256) void k_gemm1(
    const float* __restrict__ zc, const float* __restrict__ W1l,
    const float* __restrict__ b1l, float* __restrict__ z1,
    float* __restrict__ bn_acc) {
    __shared__ float w[HID * HID2];
    for (int i = threadIdx.x; i < HID * HID2; i += 256) w[i] = W1l[i];
    __syncthreads();
    int lane = threadIdx.x & 63;
    int gw = (blockIdx.x * 256 + threadIdx.x) >> 6;
    int base = gw * NPW;
    float bb0 = b1l[lane], bb1 = b1l[64 + lane];
    float s0 = 0.f, q0 = 0.f, s1 = 0.f, q1 = 0.f;
    for (int t = 0; t < NPW; ++t) {
        int i = base + t;
        if (i >= NNODES) break;
        float z = zc[(size_t)i * HID + lane];
        float p0[4] = {0.f, 0.f, 0.f, 0.f};
        float p1[4] = {0.f, 0.f, 0.f, 0.f};
#pragma unroll
        for (int kc = 0; kc < 4; kc++) {
#pragma unroll
            for (int kk = 0; kk < 16; kk++) {
                int k = kc * 16 + kk;
                float s = __shfl(z, k, 64);
                p0[kc] = fmaf(s, w[k * HID2 + lane], p0[kc]);
                p1[kc] = fmaf(s, w[k * HID2 + 64 + lane], p1[kc]);
            }
        }
        float a0 = bb0 + ((p0[0] + p0[1]) + (p0[2] + p0[3]));
        float a1 = bb1 + ((p1[0] + p1[1]) + (p1[2] + p1[3]));
        z1[(size_t)i * HID2 + lane] = a0;
        z1[(size_t)i * HID2 + 64 + lane] = a1;
        s0 += a0; q0 = fmaf(a0, a0, q0);
        s1 += a1; q1 = fmaf(a1, a1, q1);
    }
    atomicAdd(&bn_acc[lane], s0);
    atomicAdd(&bn_acc[64 + lane], s1);
    atomicAdd(&bn_acc[128 + lane], q0);
    atomicAdd(&bn_acc[192 + lane], q1);
}

__global__ void k_bnfin(const float* __restrict__ bn_acc,
                        const float* __restrict__ g1l,
                        const float* __restrict__ bt1l,
                        float* __restrict__ bn_sc) {
    int c = threadIdx.x;
    if (c >= HID2) return;
    float inv_n = 1.f / (float)NNODES;
    float mu = bn_acc[c] * inv_n;
    float ex2 = bn_acc[128 + c] * inv_n;
    float var = ex2 - mu * mu;
    float rs = rsqrtf(var + BN_EPS);
    float sc = g1l[c] * rs;
    bn_sc[c] = sc;
    bn_sc[128 + c] = bt1l[c] - mu * sc;
}

// y = relu(BN(z1)); out = LN(y @ W2 + b2); optional relu. 4 chains of 32.
__global__ __launch_bounds__(256) void k_mlp2(
    const float* __restrict__ z1, const float* __restrict__ bn_sc,
    const float* __restrict__ W2l, const float* __restrict__ b2l,
    const float* __restrict__ lngl, const float* __restrict__ lnbl,
    int do_relu, float* __restrict__ out) {
    __shared__ float w[HID2 * HID];
    for (int i = threadIdx.x; i < HID2 * HID; i += 256) w[i] = W2l[i];
    __syncthreads();
    int lane = threadIdx.x & 63;
    int gw = (blockIdx.x * 256 + threadIdx.x) >> 6;
    int base = gw * NPW;
    float sc0 = bn_sc[lane], sc1 = bn_sc[64 + lane];
    float sh0 = bn_sc[128 + lane], sh1 = bn_sc[192 + lane];
    float bb = b2l[lane], lg = lngl[lane], lb = lnbl[lane];
    for (int t = 0; t < NPW; ++t) {
        int i = base + t;
        if (i >= NNODES) break;
        float y0 = fmaxf(fmaf(z1[(size_t)i * HID2 + lane], sc0, sh0), 0.f);
        float y1 = fmaxf(fmaf(z1[(size_t)i * HID2 + 64 + lane], sc1, sh1), 0.f);
        float p[4] = {0.f, 0.f, 0.f, 0.f};
#pragma unroll
        for (int kc = 0; kc < 2; kc++) {
#pragma unroll
            for (int kk = 0; kk < 32; kk++) {
                int k = kc * 32 + kk;
                float s = __shfl(y0, k, 64);
                p[kc] = fmaf(s, w[k * HID + lane], p[kc]);
            }
        }
#pragma unroll
        for (int kc = 0; kc < 2; kc++) {
#pragma unroll
            for (int kk = 0; kk < 32; kk++) {
                int k = kc * 32 + kk;
                float s = __shfl(y1, k, 64);
                p[2 + kc] = fmaf(s, w[(64 + k) * HID + lane], p[2 + kc]);
            }
        }
        float a = bb + ((p[0] + p[1]) + (p[2] + p[3]));
        float m = wave_sum64(a) * (1.f / 64.f);
        float t0 = a - m;
        float v = wave_sum64(t0 * t0) * (1.f / 64.f);
        float o = t0 * rsqrtf(v + LN_EPS) * lg + lb;
        if (do_relu) o = fmaxf(o, 0.f);
        out[(size_t)i * HID + lane] = o;
    }
}

extern "C" void kernel_launch(void* const* d_in, const int* in_sizes, int n_in,
                              void* d_out, int out_size, void* d_ws, size_t ws_size,
                              hipStream_t stream) {
    const float* x   = (const float*)d_in[0];
    const int*   ei  = (const int*)d_in[1];
    const float* eat = (const float*)d_in[2];
    const float* Wx  = (const float*)d_in[3];
    const float* bx  = (const float*)d_in[4];
    const float* We  = (const float*)d_in[5];
    const float* be  = (const float*)d_in[6];
    const float* W1  = (const float*)d_in[7];
    const float* b1  = (const float*)d_in[8];
    const float* g1  = (const float*)d_in[9];
    const float* bt1 = (const float*)d_in[10];
    const float* W2  = (const float*)d_in[11];
    const float* b2  = (const float*)d_in[12];
    const float* eps = (const float*)d_in[13];
    const float* lng = (const float*)d_in[14];
    const float* lnb = (const float*)d_in[15];
    const int* row = ei;
    const int* col = ei + NEDGES;

    char* p = (char*)d_ws;
    auto alloc = [&](size_t bytes) -> char* {
        char* r = p;
        p += (bytes + 255) & ~(size_t)255;
        return r;
    };
    float* h       = (float*)alloc((size_t)NNODES * HID * 4);
    float* zc      = (float*)alloc((size_t)NNODES * HID * 4);
    float* z1      = (float*)alloc((size_t)NNODES * HID2 * 4);
    int*   row_off = (int*)alloc((size_t)(NNODES + 1) * 4);
    int*   srow    = (int*)alloc((size_t)NEDGES * 4);
    unsigned short* eas = (unsigned short*)alloc((size_t)NEDGES * HID * 2);
    float* bn_acc  = (float*)alloc(256 * 4);
    float* bn_sc   = (float*)alloc(256 * 4);
    // preamble-only buffers overlaid into z1's region (z1 first written after preamble)
    int* cursor = (int*)z1;                       // NNODES ints
    int* seid   = (int*)z1 + NNODES;              // NEDGES ints
    int* bsum   = (int*)z1 + NNODES + NEDGES;     // NB ints
    int* boff   = bsum + NB;                      // NB ints
    (void)ws_size; (void)in_sizes; (void)n_in; (void)out_size;

    // ---- one-time per call: node embed + CSR build + edge embed (bf16, CSR order)
    hipMemsetAsync(cursor, 0, (size_t)NNODES * 4, stream);
    k_node_embed<<<(NNODES + 3) / 4, 256, 0, stream>>>(x, Wx, bx, h);
    k_hist<<<(NEDGES + 255) / 256, 256, 0, stream>>>(col, cursor);
    k_scan1<<<NB, 256, 0, stream>>>(cursor, bsum);
    k_scan2<<<1, 512, 0, stream>>>(bsum, boff);
    k_scan3<<<NB, 256, 0, stream>>>(cursor, boff, row_off);
    k_copy<<<NB, 256, 0, stream>>>(row_off, cursor);
    k_scatter<<<(NEDGES + 255) / 256, 256, 0, stream>>>(row, col, cursor, srow, seid);
    k_edge_embed<<<(NEDGES + 3) / 4, 256, 0, stream>>>(eat, seid, We, be, eas);

    // ---- layers ----
    const int msg_blocks = (NNODES + 3) / 4;
    const int mlp_blocks = ((NNODES + NPW - 1) / NPW + 3) / 4;
    for (int l = 0; l < DEPTH; ++l) {
        k_msg<<<msg_blocks, 256, 0, stream>>>(h, row_off, srow, eas, eps + l, zc);
        hipMemsetAsync(bn_acc, 0, 256 * 4, stream);
        k_gemm1<<<mlp_blocks, 256, 0, stream>>>(zc, W1 + (size_t)l * HID * HID2,
                                                b1 + (size_t)l * HID2, z1, bn_acc);
        k_bnfin<<<1, 128, 0, stream>>>(bn_acc, g1 + (size_t)l * HID2,
                                       bt1 + (size_t)l * HID2, bn_sc);
        float* outp = (l == DEPTH - 1) ? (float*)d_out : h;
        k_mlp2<<<mlp_blocks, 256, 0, stream>>>(z1, bn_sc, W2 + (size_t)l * HID2 * HID,
                                               b2 + (size_t)l * HID,
                                               lng + (size_t)l * HID, lnb + (size_t)l * HID,
                                               (l < DEPTH - 1) ? 1 : 0, outp);
    }
}

// Round 3
// 1839.164 us; speedup vs baseline: 1.3114x; 1.1157x over previous
//
#include <hip/hip_runtime.h>
#include <hip/hip_bf16.h>
#include <cstdint>

#define NNODES 80000
#define NEDGES 1280000
#define INDIM 32
#define EDIM 16
#define HID 64
#define HID2 128
#define DEPTH 4
#define BN_EPS 1e-5f
#define LN_EPS 1e-5f
#define NB 313         // ceil(80000/256)
#define NPW 16         // nodes per wave in MLP kernels

__device__ __forceinline__ float wave_sum64(float v) {
#pragma unroll
    for (int o = 32; o > 0; o >>= 1) v += __shfl_xor(v, o, 64);
    return v;
}

__device__ __forceinline__ float bf2f(unsigned short u) {
    union { float f; uint32_t i; } c;
    c.i = ((uint32_t)u) << 16;
    return c.f;
}

__device__ __forceinline__ unsigned short f2bf(float f) {
    __hip_bfloat16 b = __float2bfloat16(f);
    return *(unsigned short*)&b;
}

// h = relu(x @ Wx + bx); one wave per node, lane = out channel
__global__ __launch_bounds__(256) void k_node_embed(
    const float* __restrict__ x, const float* __restrict__ Wx,
    const float* __restrict__ bx, float* __restrict__ h) {
    int gw = (blockIdx.x * 256 + threadIdx.x) >> 6;
    int lane = threadIdx.x & 63;
    if (gw >= NNODES) return;
    float xv = (lane < INDIM) ? x[(size_t)gw * INDIM + lane] : 0.f;
    float acc = bx[lane];
#pragma unroll
    for (int k = 0; k < INDIM; k++)
        acc = fmaf(__shfl(xv, k, 64), Wx[k * HID + lane], acc);
    h[(size_t)gw * HID + lane] = fmaxf(acc, 0.f);
}

__global__ __launch_bounds__(256) void k_hist(const int* __restrict__ col, int* __restrict__ deg) {
    int e = blockIdx.x * 256 + threadIdx.x;
    if (e < NEDGES) atomicAdd(&deg[col[e]], 1);
}

__global__ __launch_bounds__(256) void k_scan1(const int* __restrict__ deg, int* __restrict__ bsum) {
    __shared__ int s[256];
    int i = blockIdx.x * 256 + threadIdx.x;
    int v = (i < NNODES) ? deg[i] : 0;
    s[threadIdx.x] = v;
    __syncthreads();
    for (int o = 128; o > 0; o >>= 1) {
        if (threadIdx.x < o) s[threadIdx.x] += s[threadIdx.x + o];
        __syncthreads();
    }
    if (threadIdx.x == 0) bsum[blockIdx.x] = s[0];
}

__global__ __launch_bounds__(512) void k_scan2(const int* __restrict__ bsum, int* __restrict__ boff) {
    __shared__ int s[512];
    int t = threadIdx.x;
    s[t] = (t < NB) ? bsum[t] : 0;
    __syncthreads();
    for (int o = 1; o < 512; o <<= 1) {
        int v = (t >= o) ? s[t - o] : 0;
        __syncthreads();
        s[t] += v;
        __syncthreads();
    }
    if (t < NB) boff[t] = (t == 0) ? 0 : s[t - 1];
}

__global__ __launch_bounds__(256) void k_scan3(const int* __restrict__ deg,
                                               const int* __restrict__ boff,
                                               int* __restrict__ row_off) {
    __shared__ int s[256];
    int i = blockIdx.x * 256 + threadIdx.x;
    int t = threadIdx.x;
    int v = (i < NNODES) ? deg[i] : 0;
    s[t] = v;
    __syncthreads();
    for (int o = 1; o < 256; o <<= 1) {
        int u = (t >= o) ? s[t - o] : 0;
        __syncthreads();
        s[t] += u;
        __syncthreads();
    }
    int incl = s[t];
    if (i < NNODES) row_off[i] = boff[blockIdx.x] + incl - v;
    if (i == NNODES - 1) row_off[NNODES] = boff[blockIdx.x] + incl;
}

__global__ __launch_bounds__(256) void k_copy(const int* __restrict__ src, int* __restrict__ dst) {
    int i = blockIdx.x * 256 + threadIdx.x;
    if (i < NNODES) dst[i] = src[i];
}

__global__ __launch_bounds__(256) void k_scatter(const int* __restrict__ row,
                                                 const int* __restrict__ col,
                                                 int* __restrict__ cursor,
                                                 int* __restrict__ srow,
                                                 int* __restrict__ seid) {
    int e = blockIdx.x * 256 + threadIdx.x;
    if (e < NEDGES) {
        int c = col[e];
        int pos = atomicAdd(&cursor[c], 1);
        srow[pos] = row[e];
        seid[pos] = e;
    }
}

// ea[pos] = relu(edge_attr[seid[pos]] @ We + be), bf16, CSR order.
// One THREAD per edge: 64B gather, 64 outputs from LDS-transposed We.
__global__ __launch_bounds__(256) void k_edge_embed(
    const float* __restrict__ eat, const int* __restrict__ seid,
    const float* __restrict__ We, const float* __restrict__ be,
    unsigned short* __restrict__ eas) {
    __shared__ float wT[HID * EDIM];   // wT[o*16+k] = We[k*64+o]
    __shared__ float bs[HID];
    for (int i = threadIdx.x; i < HID * EDIM; i += 256) {
        int k = i & 15, o = i >> 4;
        wT[i] = We[k * HID + o];
    }
    if (threadIdx.x < HID) bs[threadIdx.x] = be[threadIdx.x];
    __syncthreads();
    int e = blockIdx.x * 256 + threadIdx.x;
    if (e >= NEDGES) return;
    int src = seid[e];
    const float4* ar = (const float4*)(eat + (size_t)src * EDIM);
    float4 a0 = ar[0], a1 = ar[1], a2 = ar[2], a3 = ar[3];
    float ev[16] = {a0.x, a0.y, a0.z, a0.w, a1.x, a1.y, a1.z, a1.w,
                    a2.x, a2.y, a2.z, a2.w, a3.x, a3.y, a3.z, a3.w};
    uint32_t outp[32];
#pragma unroll
    for (int o2 = 0; o2 < 32; o2++) {
        float acc[2];
#pragma unroll
        for (int half = 0; half < 2; half++) {
            int o = o2 * 2 + half;
            const float4* w4 = (const float4*)&wT[o * 16];
            float4 w0 = w4[0], w1 = w4[1], w2 = w4[2], w3 = w4[3];
            float p0 = fmaf(ev[3], w0.w, fmaf(ev[2], w0.z, fmaf(ev[1], w0.y, ev[0] * w0.x)));
            float p1 = fmaf(ev[7], w1.w, fmaf(ev[6], w1.z, fmaf(ev[5], w1.y, ev[4] * w1.x)));
            float p2 = fmaf(ev[11], w2.w, fmaf(ev[10], w2.z, fmaf(ev[9], w2.y, ev[8] * w2.x)));
            float p3 = fmaf(ev[15], w3.w, fmaf(ev[14], w3.z, fmaf(ev[13], w3.y, ev[12] * w3.x)));
            acc[half] = fmaxf(bs[o] + ((p0 + p1) + (p2 + p3)), 0.f);
        }
        outp[o2] = (uint32_t)f2bf(acc[0]) | ((uint32_t)f2bf(acc[1]) << 16);
    }
    uint4* dst = (uint4*)(eas + (size_t)e * HID);
#pragma unroll
    for (int q = 0; q < 8; q++)
        dst[q] = make_uint4(outp[q * 4], outp[q * 4 + 1], outp[q * 4 + 2], outp[q * 4 + 3]);
}

// zc[i] = (1+eps)*h[i] + sum_{e in CSR[i]} relu(h[srow[e]] + ea[e])
// unroll 8 for memory-level parallelism
__global__ __launch_bounds__(256) void k_msg(
    const float* __restrict__ h, const int* __restrict__ row_off,
    const int* __restrict__ srow, const unsigned short* __restrict__ eas,
    const float* __restrict__ epsp, float* __restrict__ zc) {
    int gw = (blockIdx.x * 256 + threadIdx.x) >> 6;
    int lane = threadIdx.x & 63;
    if (gw >= NNODES) return;
    int beg = row_off[gw], end = row_off[gw + 1];
    float acc = 0.f;
    int e = beg;
    for (; e + 7 < end; e += 8) {
        int j[8];
#pragma unroll
        for (int u = 0; u < 8; u++) j[u] = srow[e + u];
        float hv[8], ev[8];
#pragma unroll
        for (int u = 0; u < 8; u++) hv[u] = h[(size_t)j[u] * HID + lane];
#pragma unroll
        for (int u = 0; u < 8; u++) ev[u] = bf2f(eas[(size_t)(e + u) * HID + lane]);
        float t0 = fmaxf(hv[0] + ev[0], 0.f) + fmaxf(hv[1] + ev[1], 0.f);
        float t1 = fmaxf(hv[2] + ev[2], 0.f) + fmaxf(hv[3] + ev[3], 0.f);
        float t2 = fmaxf(hv[4] + ev[4], 0.f) + fmaxf(hv[5] + ev[5], 0.f);
        float t3 = fmaxf(hv[6] + ev[6], 0.f) + fmaxf(hv[7] + ev[7], 0.f);
        acc += (t0 + t1) + (t2 + t3);
    }
    for (; e + 3 < end; e += 4) {
        int j[4];
#pragma unroll
        for (int u = 0; u < 4; u++) j[u] = srow[e + u];
        float hv[4], ev[4];
#pragma unroll
        for (int u = 0; u < 4; u++) hv[u] = h[(size_t)j[u] * HID + lane];
#pragma unroll
        for (int u = 0; u < 4; u++) ev[u] = bf2f(eas[(size_t)(e + u) * HID + lane]);
        acc += (fmaxf(hv[0] + ev[0], 0.f) + fmaxf(hv[1] + ev[1], 0.f)) +
               (fmaxf(hv[2] + ev[2], 0.f) + fmaxf(hv[3] + ev[3], 0.f));
    }
    for (; e < end; ++e) {
        int j = srow[e];
        float hv = h[(size_t)j * HID + lane];
        float ev = bf2f(eas[(size_t)e * HID + lane]);
        acc += fmaxf(hv + ev, 0.f);
    }
    float epsl = *epsp;
    float hv0 = h[(size_t)gw * HID + lane];
    zc[(size_t)gw * HID + lane] = (1.f + epsl) * hv0 + acc;
}

// z1 = zc @ W1 + b1 ; accumulate BN sums. 4 independent FMA chains per output.
__global__ __launch_bounds__(256) void k_gemm1(
    const float* __restrict__ zc, const float* __restrict__ W1l,
    const float* __restrict__ b1l, float* __restrict__ z1,
    float* __restrict__ bn_acc) {
    __shared__ float w[HID * HID2];
    for (int i = threadIdx.x; i < HID * HID2; i += 256) w[i] = W1l[i];
    __syncthreads();
    int lane = threadIdx.x & 63;
    int gw = (blockIdx.x * 256 + threadIdx.x) >> 6;
    int base = gw * NPW;
    float bb0 = b1l[lane], bb1 = b1l[64 + lane];
    float s0 = 0.f, q0 = 0.f, s1 = 0.f, q1 = 0.f;
    for (int t = 0; t < NPW; ++t) {
        int i = base + t;
        if (i >= NNODES) break;
        float z = zc[(size_t)i * HID + lane];
        float p0[4] = {0.f, 0.f, 0.f, 0.f};
        float p1[4] = {0.f, 0.f, 0.f, 0.f};
#pragma unroll
        for (int kc = 0; kc < 4; kc++) {
#pragma unroll
            for (int kk = 0; kk < 16; kk++) {
                int k = kc * 16 + kk;
                float s = __shfl(z, k, 64);
                p0[kc] = fmaf(s, w[k * HID2 + lane], p0[kc]);
                p1[kc] = fmaf(s, w[k * HID2 + 64 + lane], p1[kc]);
            }
        }
        float a0 = bb0 + ((p0[0] + p0[1]) + (p0[2] + p0[3]));
        float a1 = bb1 + ((p1[0] + p1[1]) + (p1[2] + p1[3]));
        z1[(size_t)i * HID2 + lane] = a0;
        z1[(size_t)i * HID2 + 64 + lane] = a1;
        s0 += a0; q0 = fmaf(a0, a0, q0);
        s1 += a1; q1 = fmaf(a1, a1, q1);
    }
    atomicAdd(&bn_acc[lane], s0);
    atomicAdd(&bn_acc[64 + lane], s1);
    atomicAdd(&bn_acc[128 + lane], q0);
    atomicAdd(&bn_acc[192 + lane], q1);
}

__global__ void k_bnfin(const float* __restrict__ bn_acc,
                        const float* __restrict__ g1l,
                        const float* __restrict__ bt1l,
                        float* __restrict__ bn_sc) {
    int c = threadIdx.x;
    if (c >= HID2) return;
    float inv_n = 1.f / (float)NNODES;
    float mu = bn_acc[c] * inv_n;
    float ex2 = bn_acc[128 + c] * inv_n;
    float var = ex2 - mu * mu;
    float rs = rsqrtf(var + BN_EPS);
    float sc = g1l[c] * rs;
    bn_sc[c] = sc;
    bn_sc[128 + c] = bt1l[c] - mu * sc;
}

// y = relu(BN(z1)); out = LN(y @ W2 + b2); optional relu. 4 chains of 32.
__global__ __launch_bounds__(256) void k_mlp2(
    const float* __restrict__ z1, const float* __restrict__ bn_sc,
    const float* __restrict__ W2l, const float* __restrict__ b2l,
    const float* __restrict__ lngl, const float* __restrict__ lnbl,
    int do_relu, float* __restrict__ out) {
    __shared__ float w[HID2 * HID];
    for (int i = threadIdx.x; i < HID2 * HID; i += 256) w[i] = W2l[i];
    __syncthreads();
    int lane = threadIdx.x & 63;
    int gw = (blockIdx.x * 256 + threadIdx.x) >> 6;
    int base = gw * NPW;
    float sc0 = bn_sc[lane], sc1 = bn_sc[64 + lane];
    float sh0 = bn_sc[128 + lane], sh1 = bn_sc[192 + lane];
    float bb = b2l[lane], lg = lngl[lane], lb = lnbl[lane];
    for (int t = 0; t < NPW; ++t) {
        int i = base + t;
        if (i >= NNODES) break;
        float y0 = fmaxf(fmaf(z1[(size_t)i * HID2 + lane], sc0, sh0), 0.f);
        float y1 = fmaxf(fmaf(z1[(size_t)i * HID2 + 64 + lane], sc1, sh1), 0.f);
        float p[4] = {0.f, 0.f, 0.f, 0.f};
#pragma unroll
        for (int kc = 0; kc < 2; kc++) {
#pragma unroll
            for (int kk = 0; kk < 32; kk++) {
                int k = kc * 32 + kk;
                float s = __shfl(y0, k, 64);
                p[kc] = fmaf(s, w[k * HID + lane], p[kc]);
            }
        }
#pragma unroll
        for (int kc = 0; kc < 2; kc++) {
#pragma unroll
            for (int kk = 0; kk < 32; kk++) {
                int k = kc * 32 + kk;
                float s = __shfl(y1, k, 64);
                p[2 + kc] = fmaf(s, w[(64 + k) * HID + lane], p[2 + kc]);
            }
        }
        float a = bb + ((p[0] + p[1]) + (p[2] + p[3]));
        float m = wave_sum64(a) * (1.f / 64.f);
        float t0 = a - m;
        float v = wave_sum64(t0 * t0) * (1.f / 64.f);
        float o = t0 * rsqrtf(v + LN_EPS) * lg + lb;
        if (do_relu) o = fmaxf(o, 0.f);
        out[(size_t)i * HID + lane] = o;
    }
}

extern "C" void kernel_launch(void* const* d_in, const int* in_sizes, int n_in,
                              void* d_out, int out_size, void* d_ws, size_t ws_size,
                              hipStream_t stream) {
    const float* x   = (const float*)d_in[0];
    const int*   ei  = (const int*)d_in[1];
    const float* eat = (const float*)d_in[2];
    const float* Wx  = (const float*)d_in[3];
    const float* bx  = (const float*)d_in[4];
    const float* We  = (const float*)d_in[5];
    const float* be  = (const float*)d_in[6];
    const float* W1  = (const float*)d_in[7];
    const float* b1  = (const float*)d_in[8];
    const float* g1  = (const float*)d_in[9];
    const float* bt1 = (const float*)d_in[10];
    const float* W2  = (const float*)d_in[11];
    const float* b2  = (const float*)d_in[12];
    const float* eps = (const float*)d_in[13];
    const float* lng = (const float*)d_in[14];
    const float* lnb = (const float*)d_in[15];
    const int* row = ei;
    const int* col = ei + NEDGES;

    char* p = (char*)d_ws;
    auto alloc = [&](size_t bytes) -> char* {
        char* r = p;
        p += (bytes + 255) & ~(size_t)255;
        return r;
    };
    float* h       = (float*)alloc((size_t)NNODES * HID * 4);
    float* zc      = (float*)alloc((size_t)NNODES * HID * 4);
    float* z1      = (float*)alloc((size_t)NNODES * HID2 * 4);
    int*   row_off = (int*)alloc((size_t)(NNODES + 1) * 4);
    int*   srow    = (int*)alloc((size_t)NEDGES * 4);
    unsigned short* eas = (unsigned short*)alloc((size_t)NEDGES * HID * 2);
    float* bn_acc  = (float*)alloc(256 * 4);
    float* bn_sc   = (float*)alloc(256 * 4);
    // preamble-only buffers overlaid into z1's region (z1 first written after preamble)
    int* cursor = (int*)z1;                       // NNODES ints
    int* seid   = (int*)z1 + NNODES;              // NEDGES ints
    int* bsum   = (int*)z1 + NNODES + NEDGES;     // NB ints
    int* boff   = bsum + NB;                      // NB ints
    (void)ws_size; (void)in_sizes; (void)n_in; (void)out_size;

    // ---- one-time per call: node embed + CSR build + edge embed (bf16, CSR order)
    hipMemsetAsync(cursor, 0, (size_t)NNODES * 4, stream);
    k_node_embed<<<(NNODES + 3) / 4, 256, 0, stream>>>(x, Wx, bx, h);
    k_hist<<<(NEDGES + 255) / 256, 256, 0, stream>>>(col, cursor);
    k_scan1<<<NB, 256, 0, stream>>>(cursor, bsum);
    k_scan2<<<1, 512, 0, stream>>>(bsum, boff);
    k_scan3<<<NB, 256, 0, stream>>>(cursor, boff, row_off);
    k_copy<<<NB, 256, 0, stream>>>(row_off, cursor);
    k_scatter<<<(NEDGES + 255) / 256, 256, 0, stream>>>(row, col, cursor, srow, seid);
    k_edge_embed<<<(NEDGES + 255) / 256, 256, 0, stream>>>(eat, seid, We, be, eas);

    // ---- layers ----
    const int msg_blocks = (NNODES + 3) / 4;
    const int mlp_blocks = ((NNODES + NPW - 1) / NPW + 3) / 4;
    for (int l = 0; l < DEPTH; ++l) {
        k_msg<<<msg_blocks, 256, 0, stream>>>(h, row_off, srow, eas, eps + l, zc);
        hipMemsetAsync(bn_acc, 0, 256 * 4, stream);
        k_gemm1<<<mlp_blocks, 256, 0, stream>>>(zc, W1 + (size_t)l * HID * HID2,
                                                b1 + (size_t)l * HID2, z1, bn_acc);
        k_bnfin<<<1, 128, 0, stream>>>(bn_acc, g1 + (size_t)l * HID2,
                                       bt1 + (size_t)l * HID2, bn_sc);
        float* outp = (l == DEPTH - 1) ? (float*)d_out : h;
        k_mlp2<<<mlp_blocks, 256, 0, stream>>>(z1, bn_sc, W2 + (size_t)l * HID2 * HID,
                                               b2 + (size_t)l * HID,
                                               lng + (size_t)l * HID, lnb + (size_t)l * HID,
                                               (l < DEPTH - 1) ? 1 : 0, outp);
    }
}

// Round 4
// 740.465 us; speedup vs baseline: 3.2573x; 2.4838x over previous
//
#include <hip/hip_runtime.h>
#include <cstdint>

typedef _Float16 half8 __attribute__((ext_vector_type(8)));
typedef float f32x4 __attribute__((ext_vector_type(4)));

#define NNODES 80000
#define NEDGES 1280000
#define INDIM 32
#define EDIM 16
#define HID 64
#define HID2 128
#define DEPTH 4
#define BN_EPS 1e-5f
#define LN_EPS 1e-5f
#define NB 313         // ceil(80000/256)

union U16x8 { uint4 v; _Float16 h[8]; };

// h = relu(x @ Wx + bx) -> f16; one wave per node, lane = out channel
__global__ __launch_bounds__(256) void k_node_embed(
    const float* __restrict__ x, const float* __restrict__ Wx,
    const float* __restrict__ bx, _Float16* __restrict__ h16) {
    int gw = (blockIdx.x * 256 + threadIdx.x) >> 6;
    int lane = threadIdx.x & 63;
    if (gw >= NNODES) return;
    float xv = (lane < INDIM) ? x[(size_t)gw * INDIM + lane] : 0.f;
    float acc = bx[lane];
#pragma unroll
    for (int k = 0; k < INDIM; k++)
        acc = fmaf(__shfl(xv, k, 64), Wx[k * HID + lane], acc);
    h16[(size_t)gw * HID + lane] = (_Float16)fmaxf(acc, 0.f);
}

// one-time: transpose+convert weights to f16. w1T[l][n(128)][k(64)], w2T[l][n(64)][k(128)]
__global__ __launch_bounds__(256) void k_prep(
    const float* __restrict__ W1, const float* __restrict__ W2,
    _Float16* __restrict__ w1T, _Float16* __restrict__ w2T) {
    int id = blockIdx.x * 256 + threadIdx.x;
    if (id < DEPTH * 128 * 64) {
        int l = id / 8192, r = id % 8192, n = r / 64, k = r % 64;
        w1T[id] = (_Float16)W1[(size_t)l * 8192 + k * 128 + n];
    } else {
        int idx = id - DEPTH * 128 * 64;
        int l = idx / 8192, r = idx % 8192, n = r / 128, k = r % 128;
        w2T[idx] = (_Float16)W2[(size_t)l * 8192 + k * 64 + n];
    }
}

__global__ __launch_bounds__(256) void k_hist(const int* __restrict__ col, int* __restrict__ deg) {
    int e = blockIdx.x * 256 + threadIdx.x;
    if (e < NEDGES) atomicAdd(&deg[col[e]], 1);
}

__global__ __launch_bounds__(256) void k_scan1(const int* __restrict__ deg, int* __restrict__ bsum) {
    __shared__ int s[256];
    int i = blockIdx.x * 256 + threadIdx.x;
    int v = (i < NNODES) ? deg[i] : 0;
    s[threadIdx.x] = v;
    __syncthreads();
    for (int o = 128; o > 0; o >>= 1) {
        if (threadIdx.x < o) s[threadIdx.x] += s[threadIdx.x + o];
        __syncthreads();
    }
    if (threadIdx.x == 0) bsum[blockIdx.x] = s[0];
}

__global__ __launch_bounds__(512) void k_scan2(const int* __restrict__ bsum, int* __restrict__ boff) {
    __shared__ int s[512];
    int t = threadIdx.x;
    s[t] = (t < NB) ? bsum[t] : 0;
    __syncthreads();
    for (int o = 1; o < 512; o <<= 1) {
        int v = (t >= o) ? s[t - o] : 0;
        __syncthreads();
        s[t] += v;
        __syncthreads();
    }
    if (t < NB) boff[t] = (t == 0) ? 0 : s[t - 1];
}

__global__ __launch_bounds__(256) void k_scan3(const int* __restrict__ deg,
                                               const int* __restrict__ boff,
                                               int* __restrict__ row_off) {
    __shared__ int s[256];
    int i = blockIdx.x * 256 + threadIdx.x;
    int t = threadIdx.x;
    int v = (i < NNODES) ? deg[i] : 0;
    s[t] = v;
    __syncthreads();
    for (int o = 1; o < 256; o <<= 1) {
        int u = (t >= o) ? s[t - o] : 0;
        __syncthreads();
        s[t] += u;
        __syncthreads();
    }
    int incl = s[t];
    if (i < NNODES) row_off[i] = boff[blockIdx.x] + incl - v;
    if (i == NNODES - 1) row_off[NNODES] = boff[blockIdx.x] + incl;
}

__global__ __launch_bounds__(256) void k_copy(const int* __restrict__ src, int* __restrict__ dst) {
    int i = blockIdx.x * 256 + threadIdx.x;
    if (i < NNODES) dst[i] = src[i];
}

__global__ __launch_bounds__(256) void k_scatter(const int* __restrict__ row,
                                                 const int* __restrict__ col,
                                                 int* __restrict__ cursor,
                                                 int* __restrict__ srow,
                                                 int* __restrict__ seid) {
    int e = blockIdx.x * 256 + threadIdx.x;
    if (e < NEDGES) {
        int c = col[e];
        int pos = atomicAdd(&cursor[c], 1);
        srow[pos] = row[e];
        seid[pos] = e;
    }
}

// ea[pos] = relu(edge_attr[seid[pos]] @ We + be), f16, CSR order. One THREAD per edge.
__global__ __launch_bounds__(256) void k_edge_embed(
    const float* __restrict__ eat, const int* __restrict__ seid,
    const float* __restrict__ We, const float* __restrict__ be,
    _Float16* __restrict__ eas) {
    __shared__ float wT[HID * EDIM];   // wT[o*16+k] = We[k*64+o]
    __shared__ float bs[HID];
    for (int i = threadIdx.x; i < HID * EDIM; i += 256) {
        int k = i & 15, o = i >> 4;
        wT[i] = We[k * HID + o];
    }
    if (threadIdx.x < HID) bs[threadIdx.x] = be[threadIdx.x];
    __syncthreads();
    int e = blockIdx.x * 256 + threadIdx.x;
    if (e >= NEDGES) return;
    int src = seid[e];
    const float4* ar = (const float4*)(eat + (size_t)src * EDIM);
    float4 a0 = ar[0], a1 = ar[1], a2 = ar[2], a3 = ar[3];
    float ev[16] = {a0.x, a0.y, a0.z, a0.w, a1.x, a1.y, a1.z, a1.w,
                    a2.x, a2.y, a2.z, a2.w, a3.x, a3.y, a3.z, a3.w};
    uint32_t outp[32];
#pragma unroll
    for (int o2 = 0; o2 < 32; o2++) {
        float acc[2];
#pragma unroll
        for (int half = 0; half < 2; half++) {
            int o = o2 * 2 + half;
            const float4* w4 = (const float4*)&wT[o * 16];
            float4 w0 = w4[0], w1 = w4[1], w2 = w4[2], w3 = w4[3];
            float p0 = fmaf(ev[3], w0.w, fmaf(ev[2], w0.z, fmaf(ev[1], w0.y, ev[0] * w0.x)));
            float p1 = fmaf(ev[7], w1.w, fmaf(ev[6], w1.z, fmaf(ev[5], w1.y, ev[4] * w1.x)));
            float p2 = fmaf(ev[11], w2.w, fmaf(ev[10], w2.z, fmaf(ev[9], w2.y, ev[8] * w2.x)));
            float p3 = fmaf(ev[15], w3.w, fmaf(ev[14], w3.z, fmaf(ev[13], w3.y, ev[12] * w3.x)));
            acc[half] = fmaxf(bs[o] + ((p0 + p1) + (p2 + p3)), 0.f);
        }
        union { _Float16 h[2]; uint32_t u; } pk;
        pk.h[0] = (_Float16)acc[0];
        pk.h[1] = (_Float16)acc[1];
        outp[o2] = pk.u;
    }
    uint4* dst = (uint4*)(eas + (size_t)e * HID);
#pragma unroll
    for (int q = 0; q < 8; q++)
        dst[q] = make_uint4(outp[q * 4], outp[q * 4 + 1], outp[q * 4 + 2], outp[q * 4 + 3]);
}

// zc[i] = (1+eps)*h[i] + sum_{e in CSR[i]} relu(h[srow[e]] + ea[e]); f16 in/out, f32 math
__global__ __launch_bounds__(256) void k_msg(
    const _Float16* __restrict__ h16, const int* __restrict__ row_off,
    const int* __restrict__ srow, const _Float16* __restrict__ eas,
    const float* __restrict__ epsp, _Float16* __restrict__ zc16) {
    int gw = (blockIdx.x * 256 + threadIdx.x) >> 6;
    int lane = threadIdx.x & 63;
    if (gw >= NNODES) return;
    int beg = row_off[gw], end = row_off[gw + 1];
    float acc = 0.f;
    int e = beg;
    for (; e + 7 < end; e += 8) {
        int j[8];
#pragma unroll
        for (int u = 0; u < 8; u++) j[u] = srow[e + u];
        float hv[8], ev[8];
#pragma unroll
        for (int u = 0; u < 8; u++) hv[u] = (float)h16[(size_t)j[u] * HID + lane];
#pragma unroll
        for (int u = 0; u < 8; u++) ev[u] = (float)eas[(size_t)(e + u) * HID + lane];
        float t0 = fmaxf(hv[0] + ev[0], 0.f) + fmaxf(hv[1] + ev[1], 0.f);
        float t1 = fmaxf(hv[2] + ev[2], 0.f) + fmaxf(hv[3] + ev[3], 0.f);
        float t2 = fmaxf(hv[4] + ev[4], 0.f) + fmaxf(hv[5] + ev[5], 0.f);
        float t3 = fmaxf(hv[6] + ev[6], 0.f) + fmaxf(hv[7] + ev[7], 0.f);
        acc += (t0 + t1) + (t2 + t3);
    }
    for (; e < end; ++e) {
        int j = srow[e];
        float hv = (float)h16[(size_t)j * HID + lane];
        float ev = (float)eas[(size_t)e * HID + lane];
        acc += fmaxf(hv + ev, 0.f);
    }
    float epsl = *epsp;
    float hv0 = (float)h16[(size_t)gw * HID + lane];
    zc16[(size_t)gw * HID + lane] = (_Float16)((1.f + epsl) * hv0 + acc);
}

// MFMA GEMM1: z1 = zc @ W1 + b1 (f16 in, f16 out) + BN sum/sumsq accumulation.
// Block = 64 nodes, 4 waves; wave computes 16 rows x 128 cols; K=64 (2 steps).
__global__ __launch_bounds__(256) void k_gemm1(
    const _Float16* __restrict__ zc16, const _Float16* __restrict__ w1Tl,
    const float* __restrict__ b1l, _Float16* __restrict__ z1,
    float* __restrict__ bn_acc) {
    __shared__ __align__(16) unsigned char At[64 * 128];    // 64 nodes x 64 f16, swizzled
    __shared__ __align__(16) unsigned char Bt[128 * 128];   // 128 cols x 64 f16, swizzled
    __shared__ float red[4][HID2][2];
    int tid = threadIdx.x;
    int nb = blockIdx.x * 64;
    // stage A (zc tile): 512 chunks of 16B
#pragma unroll
    for (int i = 0; i < 2; i++) {
        int id = tid + 256 * i;
        int node = id >> 3, c = id & 7;
        uint4 v = *(const uint4*)(zc16 + (size_t)(nb + node) * HID + c * 8);
        *(uint4*)(At + node * 128 + ((c ^ (node & 7)) << 4)) = v;
    }
    // stage B (w1T): 1024 chunks
#pragma unroll
    for (int i = 0; i < 4; i++) {
        int id = tid + 256 * i;
        int r = id >> 3, c = id & 7;
        uint4 v = *(const uint4*)(w1Tl + (size_t)r * HID + c * 8);
        *(uint4*)(Bt + r * 128 + ((c ^ (r & 7)) << 4)) = v;
    }
    __syncthreads();
    int lane = tid & 63, w = tid >> 6;
    int rl = lane & 15, b = lane >> 4;
    f32x4 acc[8];
#pragma unroll
    for (int t = 0; t < 8; t++) acc[t] = (f32x4){0.f, 0.f, 0.f, 0.f};
#pragma unroll
    for (int s = 0; s < 2; s++) {
        int arow = w * 16 + rl;
        half8 af = *(const half8*)(At + arow * 128 + (((s * 4 + b) ^ (rl & 7)) << 4));
#pragma unroll
        for (int t = 0; t < 8; t++) {
            int brow = t * 16 + rl;
            half8 bf = *(const half8*)(Bt + brow * 128 + (((s * 4 + b) ^ (rl & 7)) << 4));
            acc[t] = __builtin_amdgcn_mfma_f32_16x16x32_f16(af, bf, acc[t], 0, 0, 0);
        }
    }
    // epilogue: bias, z1 f16 store, BN partial sums
#pragma unroll
    for (int t = 0; t < 8; t++) {
        int colg = t * 16 + rl;
        float bias = b1l[colg];
        float s = 0.f, q = 0.f;
#pragma unroll
        for (int r = 0; r < 4; r++) {
            float v = acc[t][r] + bias;
            int node = nb + w * 16 + b * 4 + r;
            z1[(size_t)node * HID2 + colg] = (_Float16)v;
            s += v;
            q = fmaf(v, v, q);
        }
        s += __shfl_xor(s, 16, 64); s += __shfl_xor(s, 32, 64);
        q += __shfl_xor(q, 16, 64); q += __shfl_xor(q, 32, 64);
        if (b == 0) { red[w][colg][0] = s; red[w][colg][1] = q; }
    }
    __syncthreads();
    int ch = tid & 127, which = tid >> 7;
    float tot = red[0][ch][which] + red[1][ch][which] + red[2][ch][which] + red[3][ch][which];
    atomicAdd(&bn_acc[which * HID2 + ch], tot);
}

__global__ void k_bnfin(const float* __restrict__ bn_acc,
                        const float* __restrict__ g1l,
                        const float* __restrict__ bt1l,
                        float* __restrict__ bn_sc) {
    int c = threadIdx.x;
    if (c >= HID2) return;
    float inv_n = 1.f / (float)NNODES;
    float mu = bn_acc[c] * inv_n;
    float ex2 = bn_acc[HID2 + c] * inv_n;
    float var = ex2 - mu * mu;
    float rs = rsqrtf(var + BN_EPS);
    float sc = g1l[c] * rs;
    bn_sc[c] = sc;
    bn_sc[HID2 + c] = bt1l[c] - mu * sc;
}

// MFMA GEMM2: y = relu(BN(z1)); out = LN(y @ W2 + b2); relu if not last.
// Block = 64 nodes, 4 waves; wave: 16 rows x 64 cols; K=128 (4 steps).
__global__ __launch_bounds__(256) void k_mlp2(
    const _Float16* __restrict__ z1, const float* __restrict__ bn_sc,
    const _Float16* __restrict__ w2Tl, const float* __restrict__ b2l,
    const float* __restrict__ lngl, const float* __restrict__ lnbl,
    int last, _Float16* __restrict__ hout, float* __restrict__ fout) {
    __shared__ __align__(16) unsigned char Yt[64 * 256];   // 64 nodes x 128 f16, swizzled
    __shared__ __align__(16) unsigned char Wt[64 * 256];   // 64 cols x 128 f16, swizzled
    __shared__ float sbn[256];
    int tid = threadIdx.x;
    int nb = blockIdx.x * 64;
    sbn[tid] = bn_sc[tid];
#pragma unroll
    for (int i = 0; i < 4; i++) {
        int id = tid + 256 * i;
        int r = id >> 4, c = id & 15;
        uint4 v = *(const uint4*)(w2Tl + (size_t)r * HID2 + c * 8);
        *(uint4*)(Wt + r * 256 + ((c ^ (r & 7)) << 4)) = v;
    }
    __syncthreads();
    // stage Y = relu(BN(z1)) in f16
#pragma unroll
    for (int i = 0; i < 4; i++) {
        int id = tid + 256 * i;
        int node = id >> 4, c = id & 15;
        U16x8 u, o;
        u.v = *(const uint4*)(z1 + (size_t)(nb + node) * HID2 + c * 8);
#pragma unroll
        for (int j = 0; j < 8; j++) {
            int chn = c * 8 + j;
            float y = fmaxf(fmaf((float)u.h[j], sbn[chn], sbn[HID2 + chn]), 0.f);
            o.h[j] = (_Float16)y;
        }
        *(uint4*)(Yt + node * 256 + ((c ^ (node & 7)) << 4)) = o.v;
    }
    __syncthreads();
    int lane = tid & 63, w = tid >> 6;
    int rl = lane & 15, b = lane >> 4;
    f32x4 acc[4];
#pragma unroll
    for (int t = 0; t < 4; t++) acc[t] = (f32x4){0.f, 0.f, 0.f, 0.f};
#pragma unroll
    for (int s = 0; s < 4; s++) {
        int arow = w * 16 + rl;
        half8 af = *(const half8*)(Yt + arow * 256 + (((s * 4 + b) ^ (rl & 7)) << 4));
#pragma unroll
        for (int t = 0; t < 4; t++) {
            int brow = t * 16 + rl;
            half8 bf = *(const half8*)(Wt + brow * 256 + (((s * 4 + b) ^ (rl & 7)) << 4));
            acc[t] = __builtin_amdgcn_mfma_f32_16x16x32_f16(af, bf, acc[t], 0, 0, 0);
        }
    }
    // epilogue: bias + LayerNorm across 64 cols (16 lanes x 4 tiles)
    float a[4][4]; // [r][t]
#pragma unroll
    for (int t = 0; t < 4; t++) {
        float bias = b2l[t * 16 + rl];
#pragma unroll
        for (int r = 0; r < 4; r++) a[r][t] = acc[t][r] + bias;
    }
    float m[4], vv[4];
#pragma unroll
    for (int r = 0; r < 4; r++) {
        float s = (a[r][0] + a[r][1]) + (a[r][2] + a[r][3]);
        s += __shfl_xor(s, 1, 64); s += __shfl_xor(s, 2, 64);
        s += __shfl_xor(s, 4, 64); s += __shfl_xor(s, 8, 64);
        m[r] = s * (1.f / 64.f);
    }
#pragma unroll
    for (int r = 0; r < 4; r++) {
        float t0 = a[r][0] - m[r], t1 = a[r][1] - m[r];
        float t2 = a[r][2] - m[r], t3 = a[r][3] - m[r];
        float q = (t0 * t0 + t1 * t1) + (t2 * t2 + t3 * t3);
        q += __shfl_xor(q, 1, 64); q += __shfl_xor(q, 2, 64);
        q += __shfl_xor(q, 4, 64); q += __shfl_xor(q, 8, 64);
        vv[r] = rsqrtf(q * (1.f / 64.f) + LN_EPS);
    }
#pragma unroll
    for (int t = 0; t < 4; t++) {
        int colg = t * 16 + rl;
        float lg = lngl[colg], lb = lnbl[colg];
#pragma unroll
        for (int r = 0; r < 4; r++) {
            float o = (a[r][t] - m[r]) * vv[r] * lg + lb;
            size_t node = nb + w * 16 + b * 4 + r;
            if (last) {
                fout[node * HID + colg] = o;
            } else {
                hout[node * HID + colg] = (_Float16)fmaxf(o, 0.f);
            }
        }
    }
}

extern "C" void kernel_launch(void* const* d_in, const int* in_sizes, int n_in,
                              void* d_out, int out_size, void* d_ws, size_t ws_size,
                              hipStream_t stream) {
    const float* x   = (const float*)d_in[0];
    const int*   ei  = (const int*)d_in[1];
    const float* eat = (const float*)d_in[2];
    const float* Wx  = (const float*)d_in[3];
    const float* bx  = (const float*)d_in[4];
    const float* We  = (const float*)d_in[5];
    const float* be  = (const float*)d_in[6];
    const float* W1  = (const float*)d_in[7];
    const float* b1  = (const float*)d_in[8];
    const float* g1  = (const float*)d_in[9];
    const float* bt1 = (const float*)d_in[10];
    const float* W2  = (const float*)d_in[11];
    const float* b2  = (const float*)d_in[12];
    const float* eps = (const float*)d_in[13];
    const float* lng = (const float*)d_in[14];
    const float* lnb = (const float*)d_in[15];
    const int* row = ei;
    const int* col = ei + NEDGES;

    char* p = (char*)d_ws;
    auto alloc = [&](size_t bytes) -> char* {
        char* r = p;
        p += (bytes + 255) & ~(size_t)255;
        return r;
    };
    _Float16* h16  = (_Float16*)alloc((size_t)NNODES * HID * 2);
    _Float16* zc16 = (_Float16*)alloc((size_t)NNODES * HID * 2);
    _Float16* z1   = (_Float16*)alloc((size_t)NNODES * HID2 * 2);
    int* row_off   = (int*)alloc((size_t)(NNODES + 1) * 4);
    int* srow      = (int*)alloc((size_t)NEDGES * 4);
    _Float16* eas  = (_Float16*)alloc((size_t)NEDGES * HID * 2);
    _Float16* w1T  = (_Float16*)alloc((size_t)DEPTH * 128 * 64 * 2);
    _Float16* w2T  = (_Float16*)alloc((size_t)DEPTH * 64 * 128 * 2);
    float* bn_acc  = (float*)alloc(256 * 4);
    float* bn_sc   = (float*)alloc(256 * 4);
    // preamble-only buffers overlaid into z1's region (z1 first written in layer loop)
    int* cursor = (int*)z1;                       // NNODES ints
    int* seid   = (int*)z1 + NNODES;              // NEDGES ints
    int* bsum   = (int*)z1 + NNODES + NEDGES;     // NB ints
    int* boff   = bsum + NB;                      // NB ints
    (void)ws_size; (void)in_sizes; (void)n_in; (void)out_size;

    // ---- one-time: embeds + CSR build + weight transpose/convert ----
    hipMemsetAsync(cursor, 0, (size_t)NNODES * 4, stream);
    k_node_embed<<<(NNODES + 3) / 4, 256, 0, stream>>>(x, Wx, bx, h16);
    k_prep<<<(DEPTH * 8192 * 2) / 256, 256, 0, stream>>>(W1, W2, w1T, w2T);
    k_hist<<<(NEDGES + 255) / 256, 256, 0, stream>>>(col, cursor);
    k_scan1<<<NB, 256, 0, stream>>>(cursor, bsum);
    k_scan2<<<1, 512, 0, stream>>>(bsum, boff);
    k_scan3<<<NB, 256, 0, stream>>>(cursor, boff, row_off);
    k_copy<<<NB, 256, 0, stream>>>(row_off, cursor);
    k_scatter<<<(NEDGES + 255) / 256, 256, 0, stream>>>(row, col, cursor, srow, seid);
    k_edge_embed<<<(NEDGES + 255) / 256, 256, 0, stream>>>(eat, seid, We, be, eas);

    // ---- layers ----
    const int msg_blocks = (NNODES + 3) / 4;
    const int mm_blocks = NNODES / 64;   // 1250, exact
    for (int l = 0; l < DEPTH; ++l) {
        k_msg<<<msg_blocks, 256, 0, stream>>>(h16, row_off, srow, eas, eps + l, zc16);
        hipMemsetAsync(bn_acc, 0, 256 * 4, stream);
        k_gemm1<<<mm_blocks, 256, 0, stream>>>(zc16, w1T + (size_t)l * 8192,
                                               b1 + (size_t)l * HID2, z1, bn_acc);
        k_bnfin<<<1, 128, 0, stream>>>(bn_acc, g1 + (size_t)l * HID2,
                                       bt1 + (size_t)l * HID2, bn_sc);
        k_mlp2<<<mm_blocks, 256, 0, stream>>>(z1, bn_sc, w2T + (size_t)l * 8192,
                                              b2 + (size_t)l * HID,
                                              lng + (size_t)l * HID, lnb + (size_t)l * HID,
                                              (l == DEPTH - 1) ? 1 : 0, h16, (float*)d_out);
    }
}

// Round 5
// 730.274 us; speedup vs baseline: 3.3028x; 1.0140x over previous
//
#include <hip/hip_runtime.h>
#include <cstdint>

typedef _Float16 half8 __attribute__((ext_vector_type(8)));
typedef float f32x4 __attribute__((ext_vector_type(4)));

#define NNODES 80000
#define NEDGES 1280000
#define INDIM 32
#define EDIM 16
#define HID 64
#define HID2 128
#define DEPTH 4
#define BN_EPS 1e-5f
#define LN_EPS 1e-5f
#define NB 313         // ceil(80000/256)

union U16x8 { uint4 v; _Float16 h[8]; };

// h = relu(x @ Wx + bx) -> f16; one wave per node, lane = out channel
__global__ __launch_bounds__(256) void k_node_embed(
    const float* __restrict__ x, const float* __restrict__ Wx,
    const float* __restrict__ bx, _Float16* __restrict__ h16) {
    int gw = (blockIdx.x * 256 + threadIdx.x) >> 6;
    int lane = threadIdx.x & 63;
    if (gw >= NNODES) return;
    float xv = (lane < INDIM) ? x[(size_t)gw * INDIM + lane] : 0.f;
    float acc = bx[lane];
#pragma unroll
    for (int k = 0; k < INDIM; k++)
        acc = fmaf(__shfl(xv, k, 64), Wx[k * HID + lane], acc);
    h16[(size_t)gw * HID + lane] = (_Float16)fmaxf(acc, 0.f);
}

// one-time: transpose+convert weights to f16. w1T[l][n(128)][k(64)], w2T[l][n(64)][k(128)]
__global__ __launch_bounds__(256) void k_prep(
    const float* __restrict__ W1, const float* __restrict__ W2,
    _Float16* __restrict__ w1T, _Float16* __restrict__ w2T) {
    int id = blockIdx.x * 256 + threadIdx.x;
    if (id < DEPTH * 128 * 64) {
        int l = id / 8192, r = id % 8192, n = r / 64, k = r % 64;
        w1T[id] = (_Float16)W1[(size_t)l * 8192 + k * 128 + n];
    } else {
        int idx = id - DEPTH * 128 * 64;
        int l = idx / 8192, r = idx % 8192, n = r / 128, k = r % 128;
        w2T[idx] = (_Float16)W2[(size_t)l * 8192 + k * 64 + n];
    }
}

__global__ __launch_bounds__(256) void k_hist(const int* __restrict__ col, int* __restrict__ deg) {
    int e = blockIdx.x * 256 + threadIdx.x;
    if (e < NEDGES) atomicAdd(&deg[col[e]], 1);
}

__global__ __launch_bounds__(256) void k_scan1(const int* __restrict__ deg, int* __restrict__ bsum) {
    __shared__ int s[256];
    int i = blockIdx.x * 256 + threadIdx.x;
    int v = (i < NNODES) ? deg[i] : 0;
    s[threadIdx.x] = v;
    __syncthreads();
    for (int o = 128; o > 0; o >>= 1) {
        if (threadIdx.x < o) s[threadIdx.x] += s[threadIdx.x + o];
        __syncthreads();
    }
    if (threadIdx.x == 0) bsum[blockIdx.x] = s[0];
}

__global__ __launch_bounds__(512) void k_scan2(const int* __restrict__ bsum, int* __restrict__ boff) {
    __shared__ int s[512];
    int t = threadIdx.x;
    s[t] = (t < NB) ? bsum[t] : 0;
    __syncthreads();
    for (int o = 1; o < 512; o <<= 1) {
        int v = (t >= o) ? s[t - o] : 0;
        __syncthreads();
        s[t] += v;
        __syncthreads();
    }
    if (t < NB) boff[t] = (t == 0) ? 0 : s[t - 1];
}

__global__ __launch_bounds__(256) void k_scan3(const int* __restrict__ deg,
                                               const int* __restrict__ boff,
                                               int* __restrict__ row_off) {
    __shared__ int s[256];
    int i = blockIdx.x * 256 + threadIdx.x;
    int t = threadIdx.x;
    int v = (i < NNODES) ? deg[i] : 0;
    s[t] = v;
    __syncthreads();
    for (int o = 1; o < 256; o <<= 1) {
        int u = (t >= o) ? s[t - o] : 0;
        __syncthreads();
        s[t] += u;
        __syncthreads();
    }
    int incl = s[t];
    if (i < NNODES) row_off[i] = boff[blockIdx.x] + incl - v;
    if (i == NNODES - 1) row_off[NNODES] = boff[blockIdx.x] + incl;
}

__global__ __launch_bounds__(256) void k_copy(const int* __restrict__ src, int* __restrict__ dst) {
    int i = blockIdx.x * 256 + threadIdx.x;
    if (i < NNODES) dst[i] = src[i];
}

// single 8B packed store: (src_row, edge_id)
__global__ __launch_bounds__(256) void k_scatter(const int* __restrict__ row,
                                                 const int* __restrict__ col,
                                                 int* __restrict__ cursor,
                                                 uint2* __restrict__ sre) {
    int e = blockIdx.x * 256 + threadIdx.x;
    if (e < NEDGES) {
        int c = col[e];
        int pos = atomicAdd(&cursor[c], 1);
        sre[pos] = make_uint2((unsigned)row[e], (unsigned)e);
    }
}

// ea[pos] = relu(edge_attr[sre[pos].y] @ We + be), f16, CSR order.
// MFMA version: wave = 64 edges; K=16 zero-padded to 32; proven 16x16x32_f16 path.
__global__ __launch_bounds__(256) void k_edge_embed(
    const float* __restrict__ eat, const uint2* __restrict__ sre,
    const float* __restrict__ We, const float* __restrict__ be,
    _Float16* __restrict__ eas) {
    __shared__ __align__(16) unsigned char lds[4][5120 + 8192];
    int tid = threadIdx.x;
    int w = tid >> 6, lane = tid & 63;
    unsigned char* A = lds[w];          // 64 edges x 80B (32 f16, upper 16 = 0)
    unsigned char* O = lds[w] + 5120;   // 64 edges x 128B out (xor-swizzled)
    int ebase = blockIdx.x * 256 + w * 64;
    int b = lane >> 4, c = lane & 15;
    // B fragments: bf[t][j] = We[8b+j][t*16+c] for 8b+j<16, else 0
    half8 bf[4];
#pragma unroll
    for (int t = 0; t < 4; t++) {
        half8 v = {};
        if (b < 2) {
#pragma unroll
            for (int j = 0; j < 8; j++) {
                int k = b * 8 + j;
                v[j] = (_Float16)We[k * HID + t * 16 + c];
            }
        }
        bf[t] = v;
    }
    float bias[4];
#pragma unroll
    for (int t = 0; t < 4; t++) bias[t] = be[t * 16 + c];
    // stage A: lane gathers its edge's 16 attrs, converts f16, zero-pads K to 32
    int eid = (int)sre[ebase + lane].y;
    const float4* ar = (const float4*)(eat + (size_t)eid * EDIM);
    float4 a0 = ar[0], a1 = ar[1], a2 = ar[2], a3 = ar[3];
    U16x8 lo, hi;
    lo.h[0] = (_Float16)a0.x; lo.h[1] = (_Float16)a0.y;
    lo.h[2] = (_Float16)a0.z; lo.h[3] = (_Float16)a0.w;
    lo.h[4] = (_Float16)a1.x; lo.h[5] = (_Float16)a1.y;
    lo.h[6] = (_Float16)a1.z; lo.h[7] = (_Float16)a1.w;
    hi.h[0] = (_Float16)a2.x; hi.h[1] = (_Float16)a2.y;
    hi.h[2] = (_Float16)a2.z; hi.h[3] = (_Float16)a2.w;
    hi.h[4] = (_Float16)a3.x; hi.h[5] = (_Float16)a3.y;
    hi.h[6] = (_Float16)a3.z; hi.h[7] = (_Float16)a3.w;
    uint4 zz = make_uint4(0, 0, 0, 0);
    *(uint4*)(A + lane * 80) = lo.v;
    *(uint4*)(A + lane * 80 + 16) = hi.v;
    *(uint4*)(A + lane * 80 + 32) = zz;
    *(uint4*)(A + lane * 80 + 48) = zz;
    __syncthreads();
#pragma unroll
    for (int it = 0; it < 4; it++) {
        // A-frag: row (=edge it*16+c) , k-slots 8b..8b+7
        half8 af = *(const half8*)(A + (it * 16 + c) * 80 + b * 16);
#pragma unroll
        for (int t = 0; t < 4; t++) {
            f32x4 acc = {0.f, 0.f, 0.f, 0.f};
            acc = __builtin_amdgcn_mfma_f32_16x16x32_f16(af, bf[t], acc, 0, 0, 0);
            // D: col=lane&15 (=channel within tile), row=(lane>>4)*4+reg (=edge)
#pragma unroll
            for (int r = 0; r < 4; r++) {
                int erow = it * 16 + b * 4 + r;
                int chan = t * 16 + c;
                float v = fmaxf(acc[r] + bias[t], 0.f);
                int byteoff = (erow * 128 + chan * 2) ^ ((erow & 7) << 4);
                *(_Float16*)(O + byteoff) = (_Float16)v;
            }
        }
    }
    __syncthreads();
    // coalesced store: lane writes its edge's 128B row
    uint4* dst = (uint4*)(eas + (size_t)(ebase + lane) * HID);
#pragma unroll
    for (int q = 0; q < 8; q++)
        dst[q] = *(const uint4*)(O + ((lane * 128 + q * 16) ^ ((lane & 7) << 4)));
}

// zc[i] = (1+eps)*h[i] + sum_{e in CSR[i]} relu(h[sre[e].x] + ea[e]); f16 in/out, f32 math
__global__ __launch_bounds__(256) void k_msg(
    const _Float16* __restrict__ h16, const int* __restrict__ row_off,
    const uint2* __restrict__ sre, const _Float16* __restrict__ eas,
    const float* __restrict__ epsp, _Float16* __restrict__ zc16) {
    int gw = (blockIdx.x * 256 + threadIdx.x) >> 6;
    int lane = threadIdx.x & 63;
    if (gw >= NNODES) return;
    int beg = row_off[gw], end = row_off[gw + 1];
    float acc = 0.f;
    int e = beg;
    for (; e + 7 < end; e += 8) {
        int j[8];
#pragma unroll
        for (int u = 0; u < 8; u++) j[u] = (int)sre[e + u].x;
        float hv[8], ev[8];
#pragma unroll
        for (int u = 0; u < 8; u++) hv[u] = (float)h16[(size_t)j[u] * HID + lane];
#pragma unroll
        for (int u = 0; u < 8; u++) ev[u] = (float)eas[(size_t)(e + u) * HID + lane];
        float t0 = fmaxf(hv[0] + ev[0], 0.f) + fmaxf(hv[1] + ev[1], 0.f);
        float t1 = fmaxf(hv[2] + ev[2], 0.f) + fmaxf(hv[3] + ev[3], 0.f);
        float t2 = fmaxf(hv[4] + ev[4], 0.f) + fmaxf(hv[5] + ev[5], 0.f);
        float t3 = fmaxf(hv[6] + ev[6], 0.f) + fmaxf(hv[7] + ev[7], 0.f);
        acc += (t0 + t1) + (t2 + t3);
    }
    for (; e < end; ++e) {
        int j = (int)sre[e].x;
        float hv = (float)h16[(size_t)j * HID + lane];
        float ev = (float)eas[(size_t)e * HID + lane];
        acc += fmaxf(hv + ev, 0.f);
    }
    float epsl = *epsp;
    float hv0 = (float)h16[(size_t)gw * HID + lane];
    zc16[(size_t)gw * HID + lane] = (_Float16)((1.f + epsl) * hv0 + acc);
}

// MFMA GEMM1: z1 = zc @ W1 + b1 (f16 in, f16 out) + BN sum/sumsq accumulation.
__global__ __launch_bounds__(256) void k_gemm1(
    const _Float16* __restrict__ zc16, const _Float16* __restrict__ w1Tl,
    const float* __restrict__ b1l, _Float16* __restrict__ z1,
    float* __restrict__ bn_acc) {
    __shared__ __align__(16) unsigned char At[64 * 128];    // 64 nodes x 64 f16, swizzled
    __shared__ __align__(16) unsigned char Bt[128 * 128];   // 128 cols x 64 f16, swizzled
    __shared__ float red[4][HID2][2];
    int tid = threadIdx.x;
    int nb = blockIdx.x * 64;
#pragma unroll
    for (int i = 0; i < 2; i++) {
        int id = tid + 256 * i;
        int node = id >> 3, c = id & 7;
        uint4 v = *(const uint4*)(zc16 + (size_t)(nb + node) * HID + c * 8);
        *(uint4*)(At + node * 128 + ((c ^ (node & 7)) << 4)) = v;
    }
#pragma unroll
    for (int i = 0; i < 4; i++) {
        int id = tid + 256 * i;
        int r = id >> 3, c = id & 7;
        uint4 v = *(const uint4*)(w1Tl + (size_t)r * HID + c * 8);
        *(uint4*)(Bt + r * 128 + ((c ^ (r & 7)) << 4)) = v;
    }
    __syncthreads();
    int lane = tid & 63, w = tid >> 6;
    int rl = lane & 15, b = lane >> 4;
    f32x4 acc[8];
#pragma unroll
    for (int t = 0; t < 8; t++) acc[t] = (f32x4){0.f, 0.f, 0.f, 0.f};
#pragma unroll
    for (int s = 0; s < 2; s++) {
        int arow = w * 16 + rl;
        half8 af = *(const half8*)(At + arow * 128 + (((s * 4 + b) ^ (rl & 7)) << 4));
#pragma unroll
        for (int t = 0; t < 8; t++) {
            int brow = t * 16 + rl;
            half8 bf = *(const half8*)(Bt + brow * 128 + (((s * 4 + b) ^ (rl & 7)) << 4));
            acc[t] = __builtin_amdgcn_mfma_f32_16x16x32_f16(af, bf, acc[t], 0, 0, 0);
        }
    }
#pragma unroll
    for (int t = 0; t < 8; t++) {
        int colg = t * 16 + rl;
        float bias = b1l[colg];
        float s = 0.f, q = 0.f;
#pragma unroll
        for (int r = 0; r < 4; r++) {
            float v = acc[t][r] + bias;
            int node = nb + w * 16 + b * 4 + r;
            z1[(size_t)node * HID2 + colg] = (_Float16)v;
            s += v;
            q = fmaf(v, v, q);
        }
        s += __shfl_xor(s, 16, 64); s += __shfl_xor(s, 32, 64);
        q += __shfl_xor(q, 16, 64); q += __shfl_xor(q, 32, 64);
        if (b == 0) { red[w][colg][0] = s; red[w][colg][1] = q; }
    }
    __syncthreads();
    int ch = tid & 127, which = tid >> 7;
    float tot = red[0][ch][which] + red[1][ch][which] + red[2][ch][which] + red[3][ch][which];
    atomicAdd(&bn_acc[which * HID2 + ch], tot);
}

__global__ void k_bnfin(const float* __restrict__ bn_acc,
                        const float* __restrict__ g1l,
                        const float* __restrict__ bt1l,
                        float* __restrict__ bn_sc) {
    int c = threadIdx.x;
    if (c >= HID2) return;
    float inv_n = 1.f / (float)NNODES;
    float mu = bn_acc[c] * inv_n;
    float ex2 = bn_acc[HID2 + c] * inv_n;
    float var = ex2 - mu * mu;
    float rs = rsqrtf(var + BN_EPS);
    float sc = g1l[c] * rs;
    bn_sc[c] = sc;
    bn_sc[HID2 + c] = bt1l[c] - mu * sc;
}

// MFMA GEMM2: y = relu(BN(z1)); out = LN(y @ W2 + b2); relu if not last.
__global__ __launch_bounds__(256) void k_mlp2(
    const _Float16* __restrict__ z1, const float* __restrict__ bn_sc,
    const _Float16* __restrict__ w2Tl, const float* __restrict__ b2l,
    const float* __restrict__ lngl, const float* __restrict__ lnbl,
    int last, _Float16* __restrict__ hout, float* __restrict__ fout) {
    __shared__ __align__(16) unsigned char Yt[64 * 256];   // 64 nodes x 128 f16, swizzled
    __shared__ __align__(16) unsigned char Wt[64 * 256];   // 64 cols x 128 f16, swizzled
    __shared__ float sbn[256];
    int tid = threadIdx.x;
    int nb = blockIdx.x * 64;
    sbn[tid] = bn_sc[tid];
#pragma unroll
    for (int i = 0; i < 4; i++) {
        int id = tid + 256 * i;
        int r = id >> 4, c = id & 15;
        uint4 v = *(const uint4*)(w2Tl + (size_t)r * HID2 + c * 8);
        *(uint4*)(Wt + r * 256 + ((c ^ (r & 7)) << 4)) = v;
    }
    __syncthreads();
#pragma unroll
    for (int i = 0; i < 4; i++) {
        int id = tid + 256 * i;
        int node = id >> 4, c = id & 15;
        U16x8 u, o;
        u.v = *(const uint4*)(z1 + (size_t)(nb + node) * HID2 + c * 8);
#pragma unroll
        for (int j = 0; j < 8; j++) {
            int chn = c * 8 + j;
            float y = fmaxf(fmaf((float)u.h[j], sbn[chn], sbn[HID2 + chn]), 0.f);
            o.h[j] = (_Float16)y;
        }
        *(uint4*)(Yt + node * 256 + ((c ^ (node & 7)) << 4)) = o.v;
    }
    __syncthreads();
    int lane = tid & 63, w = tid >> 6;
    int rl = lane & 15, b = lane >> 4;
    f32x4 acc[4];
#pragma unroll
    for (int t = 0; t < 4; t++) acc[t] = (f32x4){0.f, 0.f, 0.f, 0.f};
#pragma unroll
    for (int s = 0; s < 4; s++) {
        int arow = w * 16 + rl;
        half8 af = *(const half8*)(Yt + arow * 256 + (((s * 4 + b) ^ (rl & 7)) << 4));
#pragma unroll
        for (int t = 0; t < 4; t++) {
            int brow = t * 16 + rl;
            half8 bf = *(const half8*)(Wt + brow * 256 + (((s * 4 + b) ^ (rl & 7)) << 4));
            acc[t] = __builtin_amdgcn_mfma_f32_16x16x32_f16(af, bf, acc[t], 0, 0, 0);
        }
    }
    float a[4][4]; // [r][t]
#pragma unroll
    for (int t = 0; t < 4; t++) {
        float bias = b2l[t * 16 + rl];
#pragma unroll
        for (int r = 0; r < 4; r++) a[r][t] = acc[t][r] + bias;
    }
    float m[4], vv[4];
#pragma unroll
    for (int r = 0; r < 4; r++) {
        float s = (a[r][0] + a[r][1]) + (a[r][2] + a[r][3]);
        s += __shfl_xor(s, 1, 64); s += __shfl_xor(s, 2, 64);
        s += __shfl_xor(s, 4, 64); s += __shfl_xor(s, 8, 64);
        m[r] = s * (1.f / 64.f);
    }
#pragma unroll
    for (int r = 0; r < 4; r++) {
        float t0 = a[r][0] - m[r], t1 = a[r][1] - m[r];
        float t2 = a[r][2] - m[r], t3 = a[r][3] - m[r];
        float q = (t0 * t0 + t1 * t1) + (t2 * t2 + t3 * t3);
        q += __shfl_xor(q, 1, 64); q += __shfl_xor(q, 2, 64);
        q += __shfl_xor(q, 4, 64); q += __shfl_xor(q, 8, 64);
        vv[r] = rsqrtf(q * (1.f / 64.f) + LN_EPS);
    }
#pragma unroll
    for (int t = 0; t < 4; t++) {
        int colg = t * 16 + rl;
        float lg = lngl[colg], lb = lnbl[colg];
#pragma unroll
        for (int r = 0; r < 4; r++) {
            float o = (a[r][t] - m[r]) * vv[r] * lg + lb;
            size_t node = nb + w * 16 + b * 4 + r;
            if (last) {
                fout[node * HID + colg] = o;
            } else {
                hout[node * HID + colg] = (_Float16)fmaxf(o, 0.f);
            }
        }
    }
}

extern "C" void kernel_launch(void* const* d_in, const int* in_sizes, int n_in,
                              void* d_out, int out_size, void* d_ws, size_t ws_size,
                              hipStream_t stream) {
    const float* x   = (const float*)d_in[0];
    const int*   ei  = (const int*)d_in[1];
    const float* eat = (const float*)d_in[2];
    const float* Wx  = (const float*)d_in[3];
    const float* bx  = (const float*)d_in[4];
    const float* We  = (const float*)d_in[5];
    const float* be  = (const float*)d_in[6];
    const float* W1  = (const float*)d_in[7];
    const float* b1  = (const float*)d_in[8];
    const float* g1  = (const float*)d_in[9];
    const float* bt1 = (const float*)d_in[10];
    const float* W2  = (const float*)d_in[11];
    const float* b2  = (const float*)d_in[12];
    const float* eps = (const float*)d_in[13];
    const float* lng = (const float*)d_in[14];
    const float* lnb = (const float*)d_in[15];
    const int* row = ei;
    const int* col = ei + NEDGES;

    char* p = (char*)d_ws;
    auto alloc = [&](size_t bytes) -> char* {
        char* r = p;
        p += (bytes + 255) & ~(size_t)255;
        return r;
    };
    _Float16* h16  = (_Float16*)alloc((size_t)NNODES * HID * 2);
    _Float16* zc16 = (_Float16*)alloc((size_t)NNODES * HID * 2);
    _Float16* z1   = (_Float16*)alloc((size_t)NNODES * HID2 * 2);
    int* row_off   = (int*)alloc((size_t)(NNODES + 1) * 4);
    uint2* sre     = (uint2*)alloc((size_t)NEDGES * 8);
    _Float16* eas  = (_Float16*)alloc((size_t)NEDGES * HID * 2);
    _Float16* w1T  = (_Float16*)alloc((size_t)DEPTH * 128 * 64 * 2);
    _Float16* w2T  = (_Float16*)alloc((size_t)DEPTH * 64 * 128 * 2);
    float* bn_acc  = (float*)alloc(256 * 4);
    float* bn_sc   = (float*)alloc(256 * 4);
    // preamble-only buffers overlaid into z1's region (z1 first written in layer loop)
    int* cursor = (int*)z1;                       // NNODES ints
    int* bsum   = (int*)z1 + NNODES;              // NB ints
    int* boff   = bsum + NB;                      // NB ints
    (void)ws_size; (void)in_sizes; (void)n_in; (void)out_size;

    // ---- one-time: embeds + CSR build + weight transpose/convert ----
    hipMemsetAsync(cursor, 0, (size_t)NNODES * 4, stream);
    k_node_embed<<<(NNODES + 3) / 4, 256, 0, stream>>>(x, Wx, bx, h16);
    k_prep<<<(DEPTH * 8192 * 2) / 256, 256, 0, stream>>>(W1, W2, w1T, w2T);
    k_hist<<<(NEDGES + 255) / 256, 256, 0, stream>>>(col, cursor);
    k_scan1<<<NB, 256, 0, stream>>>(cursor, bsum);
    k_scan2<<<1, 512, 0, stream>>>(bsum, boff);
    k_scan3<<<NB, 256, 0, stream>>>(cursor, boff, row_off);
    k_copy<<<NB, 256, 0, stream>>>(row_off, cursor);
    k_scatter<<<(NEDGES + 255) / 256, 256, 0, stream>>>(row, col, cursor, sre);
    k_edge_embed<<<NEDGES / 256, 256, 0, stream>>>(eat, sre, We, be, eas);

    // ---- layers ----
    const int msg_blocks = (NNODES + 3) / 4;
    const int mm_blocks = NNODES / 64;   // 1250, exact
    for (int l = 0; l < DEPTH; ++l) {
        k_msg<<<msg_blocks, 256, 0, stream>>>(h16, row_off, sre, eas, eps + l, zc16);
        hipMemsetAsync(bn_acc, 0, 256 * 4, stream);
        k_gemm1<<<mm_blocks, 256, 0, stream>>>(zc16, w1T + (size_t)l * 8192,
                                               b1 + (size_t)l * HID2, z1, bn_acc);
        k_bnfin<<<1, 128, 0, stream>>>(bn_acc, g1 + (size_t)l * HID2,
                                       bt1 + (size_t)l * HID2, bn_sc);
        k_mlp2<<<mm_blocks, 256, 0, stream>>>(z1, bn_sc, w2T + (size_t)l * 8192,
                                              b2 + (size_t)l * HID,
                                              lng + (size_t)l * HID, lnb + (size_t)l * HID,
                                              (l == DEPTH - 1) ? 1 : 0, h16, (float*)d_out);
    }
}